// Round 2
// baseline (123.514 us; speedup 1.0000x reference)
//
#include <hip/hip_runtime.h>

// Problem constants (reference: N=16384, K=32, D=256)
#define N_ 16384
#define K_ 32
#define D_ 256
#define NEG_SLOPE 0.01f

#define GRID_ 2048
#define ITER_ 8   // rows of n per block; GRID_*ITER_ == N_

// ---------------------------------------------------------------------------
// Prologue: v[e] = sum_d a_w[d] * W[d,e]   (a_w @ W, D floats)
//           ws[D] = 2*dot(b, a_w) + a_b    (scalar bias folded into score)
// ---------------------------------------------------------------------------
__global__ __launch_bounds__(1024) void prep_kernel(
    const float* __restrict__ W, const float* __restrict__ b,
    const float* __restrict__ a_w, const float* __restrict__ a_b,
    float* __restrict__ ws) {
  __shared__ float part[4][D_];
  const int t = threadIdx.x;
  const int dd = t >> 8;   // 0..3
  const int e = t & 255;
  float acc = 0.f;
#pragma unroll 8
  for (int j = 0; j < 64; ++j) {
    const int d = dd * 64 + j;
    acc += a_w[d] * W[d * D_ + e];
  }
  part[dd][e] = acc;
  __syncthreads();
  if (t < D_) ws[t] = part[0][t] + part[1][t] + part[2][t] + part[3][t];
  __syncthreads();
  if (t < D_) part[0][t] = b[t] * a_w[t];
  __syncthreads();
  if (t == 0) {
    float s = 0.f;
    for (int i = 0; i < D_; ++i) s += part[0][i];
    ws[D_] = 2.f * s + a_b[0];
  }
}

// ---------------------------------------------------------------------------
// Main: persistent-ish blocks, ITER_ rows each, register double-buffered
// prefetch (loads for n+1 in flight while n is processed). middle[n] staged
// once in LDS (XOR-swizzled float4 slots: p = s ^ (r&7)) — conflict-free
// b128 writes AND conflict-free scalar pass-2 reads.
// ---------------------------------------------------------------------------
struct Buf {
  float4 m[8];  // this thread's 8 float4 of middle[n] (row r, slots c+8i)
  float tg;     // target[n][t]
};

__device__ __forceinline__ void load_buf(
    Buf& bf, const float* __restrict__ middle, const float* __restrict__ target,
    int n, int t, int r, int c) {
  const float4* mrow = (const float4*)(middle + (size_t)n * K_ * D_);
#pragma unroll
  for (int i = 0; i < 8; ++i) bf.m[i] = mrow[r * 64 + c + i * 8];
  bf.tg = target[(size_t)n * D_ + t];
}

__device__ __forceinline__ void process(
    const Buf& bf, float* __restrict__ smid, const float* __restrict__ lv,
    float* __restrict__ sdot, float* __restrict__ stp, float* __restrict__ scoef,
    float cadd, float* __restrict__ outrow, int t, int r, int c) {
  // regs -> LDS (swizzled) + fused dot with v
  float pdot = 0.f;
#pragma unroll
  for (int i = 0; i < 8; ++i) {
    const int s = c + i * 8;
    const float4 m4 = bf.m[i];
    *(float4*)(smid + r * D_ + ((s ^ (r & 7)) * 4)) = m4;
    const float4 v4 = *(const float4*)(lv + s * 4);
    pdot += m4.x * v4.x + m4.y * v4.y + m4.z * v4.z + m4.w * v4.w;
  }
  pdot += __shfl_xor(pdot, 1);
  pdot += __shfl_xor(pdot, 2);
  pdot += __shfl_xor(pdot, 4);
  if (c == 0) sdot[r] = pdot;

  float tp = bf.tg * lv[t];
#pragma unroll
  for (int off = 1; off < 64; off <<= 1) tp += __shfl_xor(tp, off);
  if ((t & 63) == 0) stp[t >> 6] = tp;
  __syncthreads();

  // softmax over K=32 in wave 0
  if (t < 64) {
    const float tdot = stp[0] + stp[1] + stp[2] + stp[3];
    const int k = t & 31;
    float sc = sdot[k] + tdot + cadd;
    sc = sc > 0.f ? sc : NEG_SLOPE * sc;  // leaky_relu
    float mx = sc;
    mx = fmaxf(mx, __shfl_xor(mx, 1));
    mx = fmaxf(mx, __shfl_xor(mx, 2));
    mx = fmaxf(mx, __shfl_xor(mx, 4));
    mx = fmaxf(mx, __shfl_xor(mx, 8));
    mx = fmaxf(mx, __shfl_xor(mx, 16));
    float ex = __expf(sc - mx);
    float sum = ex;
    sum += __shfl_xor(sum, 1);
    sum += __shfl_xor(sum, 2);
    sum += __shfl_xor(sum, 4);
    sum += __shfl_xor(sum, 8);
    sum += __shfl_xor(sum, 16);
    if (t < 32) scoef[k] = ex / sum;
  }
  __syncthreads();

  // pass 2: out[n, t] = sum_k coef[k] * middle[n, k, t]
  float acc = 0.f;
  const int s2 = t >> 2;
  const int e2 = t & 3;
#pragma unroll
  for (int k = 0; k < K_; ++k) {
    acc += scoef[k] * smid[k * D_ + ((s2 ^ (k & 7)) * 4) + e2];
  }
  outrow[t] = acc;
  __syncthreads();  // protect smid/sdot/scoef before next iteration's writes
}

__global__ __launch_bounds__(256) void attn_agg_kernel(
    const float* __restrict__ target, const float* __restrict__ middle,
    const float* __restrict__ ws, float* __restrict__ out) {
  __shared__ __align__(16) float smid[K_ * D_];  // 32 KB
  __shared__ __align__(16) float lv[D_];
  __shared__ float sdot[K_];
  __shared__ float stp[4];
  __shared__ float scoef[K_];

  const int t = threadIdx.x;
  const int r = t >> 3;  // row k this thread loads, 0..31
  const int c = t & 7;   // lane-in-row, 0..7

  lv[t] = ws[t];
  const float cadd = ws[D_];
  __syncthreads();

  const int n0 = blockIdx.x * ITER_;

  Buf A, B;
  load_buf(A, middle, target, n0, t, r, c);

#pragma unroll 1
  for (int it = 0; it < ITER_; it += 2) {
    load_buf(B, middle, target, n0 + it + 1, t, r, c);   // prefetch n+1
    process(A, smid, lv, sdot, stp, scoef, cadd,
            out + (size_t)(n0 + it) * D_, t, r, c);
    if (it + 2 < ITER_)
      load_buf(A, middle, target, n0 + it + 2, t, r, c); // prefetch n+2
    process(B, smid, lv, sdot, stp, scoef, cadd,
            out + (size_t)(n0 + it + 1) * D_, t, r, c);
  }
}

extern "C" void kernel_launch(void* const* d_in, const int* in_sizes, int n_in,
                              void* d_out, int out_size, void* d_ws, size_t ws_size,
                              hipStream_t stream) {
  const float* target = (const float*)d_in[0];
  const float* middle = (const float*)d_in[1];
  const float* W      = (const float*)d_in[2];
  const float* b      = (const float*)d_in[3];
  const float* a_w    = (const float*)d_in[4];
  const float* a_b    = (const float*)d_in[5];
  float* out = (float*)d_out;
  float* ws  = (float*)d_ws;  // needs (D_+1) floats

  prep_kernel<<<1, 1024, 0, stream>>>(W, b, a_w, a_b, ws);
  attn_agg_kernel<<<GRID_, 256, 0, stream>>>(target, middle, ws, out);
}

// Round 3
// 113.650 us; speedup vs baseline: 1.0868x; 1.0868x over previous
//
#include <hip/hip_runtime.h>

// Problem constants (reference: N=16384, K=32, D=256)
#define N_ 16384
#define K_ 32
#define D_ 256
#define NEG_SLOPE 0.01f

// ---------------------------------------------------------------------------
// Prologue: v[e] = sum_d a_w[d] * W[d,e]   (a_w @ W, D floats)
//           ws[D] = 2*dot(b, a_w) + a_b    (scalar bias folded into score)
// ---------------------------------------------------------------------------
__global__ __launch_bounds__(1024) void prep_kernel(
    const float* __restrict__ W, const float* __restrict__ b,
    const float* __restrict__ a_w, const float* __restrict__ a_b,
    float* __restrict__ ws) {
  __shared__ float part[4][D_];
  const int t = threadIdx.x;
  const int dd = t >> 8;   // 0..3
  const int e = t & 255;
  float acc = 0.f;
#pragma unroll 8
  for (int j = 0; j < 64; ++j) {
    const int d = dd * 64 + j;
    acc += a_w[d] * W[d * D_ + e];
  }
  part[dd][e] = acc;
  __syncthreads();
  if (t < D_) ws[t] = part[0][t] + part[1][t] + part[2][t] + part[3][t];
  __syncthreads();
  if (t < D_) part[0][t] = b[t] * a_w[t];
  __syncthreads();
  if (t == 0) {
    float s = 0.f;
    for (int i = 0; i < D_; ++i) s += part[0][i];
    ws[D_] = 2.f * s + a_b[0];
  }
}

// ---------------------------------------------------------------------------
// Main: one block per n, NO LDS staging of middle. Each thread keeps its
// slice of middle[n] in registers for both passes:
//   wave kg (t>>6) owns k-rows 8kg..8kg+7; lane l (t&63) owns cols 4l..4l+3.
// Pass 1 k-dots reduced with a value-halving shuffle butterfly (17 shuffles).
// Pass 2: 32 FMAs on registers + 4KB LDS cross-wave column sum.
// LDS ~4.3KB -> occupancy VGPR-bound (~6 blocks/CU vs 4 with LDS staging).
// ---------------------------------------------------------------------------
__global__ __launch_bounds__(256) void attn_agg_kernel(
    const float* __restrict__ target, const float* __restrict__ middle,
    const float* __restrict__ ws, float* __restrict__ out) {
  __shared__ __align__(16) float part[4][D_];  // 4 KB cross-wave column sums
  __shared__ float sdot[K_];
  __shared__ float scoef[K_];
  __shared__ float stp[4];

  const int t = threadIdx.x;
  const int kg = t >> 6;   // wave id, owns k = 8kg..8kg+7
  const int l = t & 63;    // lane, owns columns 4l..4l+3
  const int n = blockIdx.x;

  // Load this thread's register slice of middle[n]: 8 float4 (32 VGPR).
  // Per j, a wave's 64 lanes read one contiguous 1KB row -> fully coalesced.
  const float4* m4p = (const float4*)(middle + (size_t)n * K_ * D_);
  float4 m[8];
#pragma unroll
  for (int j = 0; j < 8; ++j) m[j] = m4p[(kg * 8 + j) * 64 + l];

  const float4 vv = ((const float4*)ws)[l];  // v[4l..4l+3]
  const float vt = ws[t];                    // v[t]
  const float cadd = ws[D_];
  const float tg = target[(size_t)n * D_ + t];

  // Pass 1: pd[j] = partial dot(middle[n][8kg+j], v) over this lane's 4 cols
  float pd[8];
#pragma unroll
  for (int j = 0; j < 8; ++j)
    pd[j] = m[j].x * vv.x + m[j].y * vv.y + m[j].z * vv.z + m[j].w * vv.w;

  // Value-halving butterfly over the 64-lane wave (8 values -> 17 shuffles).
#pragma unroll
  for (int j = 0; j < 8; ++j) pd[j] += __shfl_xor(pd[j], 32);
  float q0 = (l & 32) ? pd[4] : pd[0];
  float q1 = (l & 32) ? pd[5] : pd[1];
  float q2 = (l & 32) ? pd[6] : pd[2];
  float q3 = (l & 32) ? pd[7] : pd[3];
  q0 += __shfl_xor(q0, 16);
  q1 += __shfl_xor(q1, 16);
  q2 += __shfl_xor(q2, 16);
  q3 += __shfl_xor(q3, 16);
  float r0 = (l & 16) ? q2 : q0;
  float r1 = (l & 16) ? q3 : q1;
  r0 += __shfl_xor(r0, 8);
  r1 += __shfl_xor(r1, 8);
  float s = (l & 8) ? r1 : r0;
  s += __shfl_xor(s, 4);
  s += __shfl_xor(s, 2);
  s += __shfl_xor(s, 1);
  // Lane l holds the full-wave sum for j = bit5*4 + bit4*2 + bit3 of l.
  if ((l & 7) == 0) {
    const int j_own = ((l >> 5) & 1) * 4 + ((l >> 4) & 1) * 2 + ((l >> 3) & 1);
    sdot[kg * 8 + j_own] = s;
  }

  // target[n] . v  (block-wide)
  float tp = tg * vt;
#pragma unroll
  for (int off = 1; off < 64; off <<= 1) tp += __shfl_xor(tp, off);
  if (l == 0) stp[kg] = tp;
  __syncthreads();

  // Softmax over K=32 in wave 0
  if (t < 64) {
    const float tdot = stp[0] + stp[1] + stp[2] + stp[3];
    const int k = t & 31;
    float sc = sdot[k] + tdot + cadd;
    sc = sc > 0.f ? sc : NEG_SLOPE * sc;  // leaky_relu
    float mx = sc;
    mx = fmaxf(mx, __shfl_xor(mx, 1));
    mx = fmaxf(mx, __shfl_xor(mx, 2));
    mx = fmaxf(mx, __shfl_xor(mx, 4));
    mx = fmaxf(mx, __shfl_xor(mx, 8));
    mx = fmaxf(mx, __shfl_xor(mx, 16));
    float ex = __expf(sc - mx);
    float sum = ex;
    sum += __shfl_xor(sum, 1);
    sum += __shfl_xor(sum, 2);
    sum += __shfl_xor(sum, 4);
    sum += __shfl_xor(sum, 8);
    sum += __shfl_xor(sum, 16);
    if (t < 32) scoef[k] = ex / sum;
  }
  __syncthreads();

  // Pass 2: per-wave partial of out columns 4l..4l+3 over this wave's 8 k's
  float4 acc = make_float4(0.f, 0.f, 0.f, 0.f);
#pragma unroll
  for (int j = 0; j < 8; ++j) {
    const float cf = scoef[kg * 8 + j];  // wave-uniform -> LDS broadcast
    acc.x += cf * m[j].x;
    acc.y += cf * m[j].y;
    acc.z += cf * m[j].z;
    acc.w += cf * m[j].w;
  }
  *(float4*)(&part[kg][4 * l]) = acc;
  __syncthreads();

  out[(size_t)n * D_ + t] = part[0][t] + part[1][t] + part[2][t] + part[3][t];
}

extern "C" void kernel_launch(void* const* d_in, const int* in_sizes, int n_in,
                              void* d_out, int out_size, void* d_ws, size_t ws_size,
                              hipStream_t stream) {
  const float* target = (const float*)d_in[0];
  const float* middle = (const float*)d_in[1];
  const float* W      = (const float*)d_in[2];
  const float* b      = (const float*)d_in[3];
  const float* a_w    = (const float*)d_in[4];
  const float* a_b    = (const float*)d_in[5];
  float* out = (float*)d_out;
  float* ws  = (float*)d_ws;  // needs (D_+1) floats

  prep_kernel<<<1, 1024, 0, stream>>>(W, b, a_w, a_b, ws);
  attn_agg_kernel<<<N_, 256, 0, stream>>>(target, middle, ws, out);
}

// Round 4
// 110.785 us; speedup vs baseline: 1.1149x; 1.0259x over previous
//
#include <hip/hip_runtime.h>

// Problem constants (reference: N=16384, K=32, D=256)
#define N_ 16384
#define K_ 32
#define D_ 256
#define NEG_SLOPE 0.01f

// ---------------------------------------------------------------------------
// Prologue (parallel): ws[0..255] = v = a_w @ W, ws[256] = 2*dot(b,a_w)+a_b.
// ws is zeroed by hipMemsetAsync first; 32 blocks accumulate via atomicAdd.
// Block i handles d-rows 8i..8i+7 (8 KB of W) -> parallel across 32 CUs
// instead of one cold single-block serial read of 256 KB.
// ---------------------------------------------------------------------------
__global__ __launch_bounds__(256) void prep_kernel(
    const float* __restrict__ W, const float* __restrict__ b,
    const float* __restrict__ a_w, const float* __restrict__ a_b,
    float* __restrict__ ws) {
  const int t = threadIdx.x;  // column e
  const int i = blockIdx.x;   // 0..31
  float acc = 0.f;
#pragma unroll
  for (int j = 0; j < 8; ++j) {
    const int d = i * 8 + j;
    acc += a_w[d] * W[d * D_ + t];
  }
  atomicAdd(&ws[t], acc);

  if (i == 0) {
    // scalar: 2*dot(b, a_w) + a_b, reduced across this block's 256 threads
    float s = b[t] * a_w[t];
#pragma unroll
    for (int off = 1; off < 64; off <<= 1) s += __shfl_xor(s, off);
    __shared__ float sp[4];
    if ((t & 63) == 0) sp[t >> 6] = s;
    __syncthreads();
    if (t == 0)
      atomicAdd(&ws[D_], 2.f * (sp[0] + sp[1] + sp[2] + sp[3]) + a_b[0]);
  }
}

// ---------------------------------------------------------------------------
// Main: one block of 512 threads per n. Wave kg (0..7) owns k-rows
// 4kg..4kg+3; lane l owns columns 4l..4l+3 -> m[4] = 16 VGPR.
// __launch_bounds__(512,8) pins VGPR <= 64 -> 32 waves/CU (4 blocks),
// 2x the occupancy of all previous rounds. LDS ~8.3 KB (not binding).
// ---------------------------------------------------------------------------
__global__ __launch_bounds__(512, 8) void attn_agg_kernel(
    const float* __restrict__ target, const float* __restrict__ middle,
    const float* __restrict__ ws, float* __restrict__ out) {
  __shared__ __align__(16) float part[8][D_];  // 8 KB cross-wave column sums
  __shared__ float sdot[K_];
  __shared__ float scoef[K_];
  __shared__ float stp[4];

  const int t = threadIdx.x;
  const int kg = t >> 6;   // wave id 0..7, owns k = 4kg..4kg+3
  const int l = t & 63;    // lane, owns columns 4l..4l+3
  const int n = blockIdx.x;

  // Load this wave's 4 k-rows: per j, 64 lanes x 16B = contiguous 1KB row.
  const float4* m4p = (const float4*)(middle + (size_t)n * K_ * D_);
  float4 m[4];
#pragma unroll
  for (int j = 0; j < 4; ++j) m[j] = m4p[(kg * 4 + j) * 64 + l];

  const float4 vv = ((const float4*)ws)[l];  // v[4l..4l+3]
  const float cadd = ws[D_];

  // Pass 1: partial dots with v, then value-halving butterfly (10 shuffles).
  float pd[4];
#pragma unroll
  for (int j = 0; j < 4; ++j)
    pd[j] = m[j].x * vv.x + m[j].y * vv.y + m[j].z * vv.z + m[j].w * vv.w;

#pragma unroll
  for (int j = 0; j < 4; ++j) pd[j] += __shfl_xor(pd[j], 32);
  float q0 = (l & 32) ? pd[2] : pd[0];
  float q1 = (l & 32) ? pd[3] : pd[1];
  q0 += __shfl_xor(q0, 16);
  q1 += __shfl_xor(q1, 16);
  float r = (l & 16) ? q1 : q0;
  r += __shfl_xor(r, 8);
  r += __shfl_xor(r, 4);
  r += __shfl_xor(r, 2);
  r += __shfl_xor(r, 1);
  // 16-lane group (l>>4) holds full sum for j = (l>>5)*2 + ((l>>4)&1)
  if ((l & 15) == 0)
    sdot[kg * 4 + ((l >> 5) * 2 + ((l >> 4) & 1))] = r;

  // target[n] . v  (waves 0..3 only: t < 256)
  if (t < D_) {
    float tp = target[(size_t)n * D_ + t] * ws[t];
#pragma unroll
    for (int off = 1; off < 64; off <<= 1) tp += __shfl_xor(tp, off);
    if (l == 0) stp[kg] = tp;
  }
  __syncthreads();

  // Softmax over K=32 in wave 0
  if (t < 64) {
    const float tdot = stp[0] + stp[1] + stp[2] + stp[3];
    const int k = t & 31;
    float sc = sdot[k] + tdot + cadd;
    sc = sc > 0.f ? sc : NEG_SLOPE * sc;  // leaky_relu
    float mx = sc;
    mx = fmaxf(mx, __shfl_xor(mx, 1));
    mx = fmaxf(mx, __shfl_xor(mx, 2));
    mx = fmaxf(mx, __shfl_xor(mx, 4));
    mx = fmaxf(mx, __shfl_xor(mx, 8));
    mx = fmaxf(mx, __shfl_xor(mx, 16));
    float ex = __expf(sc - mx);
    float sum = ex;
    sum += __shfl_xor(sum, 1);
    sum += __shfl_xor(sum, 2);
    sum += __shfl_xor(sum, 4);
    sum += __shfl_xor(sum, 8);
    sum += __shfl_xor(sum, 16);
    if (t < 32) scoef[k] = ex / sum;
  }
  __syncthreads();

  // Pass 2: wave partial over its 4 k's, columns 4l..4l+3 (registers only)
  float4 acc = make_float4(0.f, 0.f, 0.f, 0.f);
#pragma unroll
  for (int j = 0; j < 4; ++j) {
    const float cf = scoef[kg * 4 + j];  // wave-uniform broadcast
    acc.x += cf * m[j].x;
    acc.y += cf * m[j].y;
    acc.z += cf * m[j].z;
    acc.w += cf * m[j].w;
  }
  *(float4*)(&part[kg][4 * l]) = acc;
  __syncthreads();

  // Cross-wave column sum + store (threads 0..255)
  if (t < D_) {
    float o = 0.f;
#pragma unroll
    for (int w = 0; w < 8; ++w) o += part[w][t];
    out[(size_t)n * D_ + t] = o;
  }
}

extern "C" void kernel_launch(void* const* d_in, const int* in_sizes, int n_in,
                              void* d_out, int out_size, void* d_ws, size_t ws_size,
                              hipStream_t stream) {
  const float* target = (const float*)d_in[0];
  const float* middle = (const float*)d_in[1];
  const float* W      = (const float*)d_in[2];
  const float* b      = (const float*)d_in[3];
  const float* a_w    = (const float*)d_in[4];
  const float* a_b    = (const float*)d_in[5];
  float* out = (float*)d_out;
  float* ws  = (float*)d_ws;  // needs (D_+1) floats

  hipMemsetAsync(ws, 0, (D_ + 1) * sizeof(float), stream);
  prep_kernel<<<32, 256, 0, stream>>>(W, b, a_w, a_b, ws);
  attn_agg_kernel<<<N_, 512, 0, stream>>>(target, middle, ws, out);
}